// Round 7
// baseline (13702.113 us; speedup 1.0000x reference)
//
#include <hip/hip_runtime.h>
#include <cstdint>
#include <cstddef>

#define T_LEN 512
#define S_LEN 512
#define HID   1024
#define AD    256
#define VOC   50257
#define G3    3072
#define NWG   128
#define NT    512
#define NPART (197*4)

typedef unsigned long long u64;

// ---------------- workspace layout (float offsets) ----------------
#define WS_GENC   0
#define WS_GITOK  (WS_GENC + G3*S_LEN)
#define WS_EX     (WS_GITOK + T_LEN*G3)
#define WS_H1     (WS_EX + S_LEN*AD)
#define WS_FC1    (WS_H1 + T_LEN*HID)
#define WS_ROWP   (WS_FC1 + T_LEN*32)
#define WS_INV    (WS_ROWP + T_LEN*NPART)
#define WS_TAGF   (((WS_INV + T_LEN) + 15) & ~15)   // 64B-aligned

// ---- tagged-dataflow region: one 64B line (8 u64) per producer WG per class ----
// LNH0[c][p][0..7]=nh0 cols 8p.., LNH1 same, LW[c][p][0..3]=w rows 4p..,
// LEU[c][p]={e0p, u0[2p], u0[2p+1], e1p, u1[2p], u1[2p+1], -, -}
#define TG_NH0 0
#define TG_NH1 (TG_NH0 + 2*NWG*8)
#define TG_W   (TG_NH1 + 2*NWG*8)
#define TG_EU  (TG_W   + 2*NWG*8)
#define TG_TOT (TG_EU  + 2*NWG*8)                    // 8192 u64 = 64KB

__device__ inline float wred64(float v) {
  v += __shfl_xor(v, 32, 64); v += __shfl_xor(v, 16, 64); v += __shfl_xor(v, 8, 64);
  v += __shfl_xor(v, 4, 64);  v += __shfl_xor(v, 2, 64);  v += __shfl_xor(v, 1, 64);
  return v;
}
__device__ inline float fast_sigmoid(float x) { return 1.f / (1.f + __expf(-x)); }
__device__ inline float fast_tanh(float x) {
  float e = __expf(2.f * x);
  return 1.f - 2.f / (e + 1.f);
}

__device__ inline u64 ald(const u64* p) {
  return __hip_atomic_load(p, __ATOMIC_RELAXED, __HIP_MEMORY_SCOPE_AGENT);
}
__device__ inline void stq(u64* p, float v, unsigned tag) {
  __hip_atomic_store(p, ((u64)tag << 32) | (u64)__float_as_uint(v),
                     __ATOMIC_RELAXED, __HIP_MEMORY_SCOPE_AGENT);
}
#define LO_F(x) __uint_as_float((unsigned)(x))
#define TAGOK(x, t) (((unsigned)((x) >> 32)) == (t))

__device__ inline float qdot4(const float4& a0, const float4& a1, const float4& a2, const float4& a3,
                              const float4& x0, const float4& x1, const float4& x2, const float4& x3) {
  float a = 0.f;
  a = fmaf(a0.x, x0.x, a); a = fmaf(a0.y, x0.y, a); a = fmaf(a0.z, x0.z, a); a = fmaf(a0.w, x0.w, a);
  a = fmaf(a1.x, x1.x, a); a = fmaf(a1.y, x1.y, a); a = fmaf(a1.z, x1.z, a); a = fmaf(a1.w, x1.w, a);
  a = fmaf(a2.x, x2.x, a); a = fmaf(a2.y, x2.y, a); a = fmaf(a2.z, x2.z, a); a = fmaf(a2.w, x2.w, a);
  a = fmaf(a3.x, x3.x, a); a = fmaf(a3.y, x3.y, a); a = fmaf(a3.z, x3.z, a); a = fmaf(a3.w, x3.w, a);
  return a;
}
__device__ inline float qdot2(const float4& a0, const float4& a1,
                              const float4& x0, const float4& x1) {
  float a = 0.f;
  a = fmaf(a0.x, x0.x, a); a = fmaf(a0.y, x0.y, a); a = fmaf(a0.z, x0.z, a); a = fmaf(a0.w, x0.w, a);
  a = fmaf(a1.x, x1.x, a); a = fmaf(a1.y, x1.y, a); a = fmaf(a1.z, x1.z, a); a = fmaf(a1.w, x1.w, a);
  return a;
}

// ---------------- init: zero all tag words ----------------
__global__ void k_init(float* ws) {
  u64* TG = (u64*)(ws + WS_TAGF);
  const int i = blockIdx.x * 256 + threadIdx.x;
  if (i < TG_TOT) TG[i] = 0ull;
}

// ---------------- generic tiled fp32 GEMM (pre/post passes) ----------------
__global__ __launch_bounds__(256) void k_gemm(
    const float* __restrict__ A, int lda, const int* __restrict__ gidx,
    const float* __restrict__ B, int ldb, int kofs,
    const float* __restrict__ bias, float* __restrict__ C, int ldc,
    int M, int N, int act)
{
  __shared__ float As[64][33];
  __shared__ float Bs[64][33];
  const int bm = blockIdx.y * 64, bn = blockIdx.x * 64;
  const int tx = threadIdx.x & 15, ty = threadIdx.x >> 4;
  float acc[4][4] = {};
  const int lin = threadIdx.x * 8;
  const int lr = lin >> 5;
  const int lc = lin & 31;
  for (int k0 = 0; k0 < 1024; k0 += 32) {
    {
      const int gm = bm + lr;
      float4 v0 = {0,0,0,0}, v1 = {0,0,0,0};
      if (gm < M) {
        const int row = gidx ? gidx[gm] : gm;
        const float* p = A + (size_t)row * lda + k0 + lc;
        v0 = *(const float4*)p; v1 = *(const float4*)(p + 4);
      }
      As[lr][lc+0]=v0.x; As[lr][lc+1]=v0.y; As[lr][lc+2]=v0.z; As[lr][lc+3]=v0.w;
      As[lr][lc+4]=v1.x; As[lr][lc+5]=v1.y; As[lr][lc+6]=v1.z; As[lr][lc+7]=v1.w;
    }
    {
      const int gn = bn + lr;
      float4 v0 = {0,0,0,0}, v1 = {0,0,0,0};
      if (gn < N) {
        const float* p = B + (size_t)gn * ldb + kofs + k0 + lc;
        v0 = *(const float4*)p; v1 = *(const float4*)(p + 4);
      }
      Bs[lr][lc+0]=v0.x; Bs[lr][lc+1]=v0.y; Bs[lr][lc+2]=v0.z; Bs[lr][lc+3]=v0.w;
      Bs[lr][lc+4]=v1.x; Bs[lr][lc+5]=v1.y; Bs[lr][lc+6]=v1.z; Bs[lr][lc+7]=v1.w;
    }
    __syncthreads();
    #pragma unroll
    for (int kk = 0; kk < 32; ++kk) {
      float a0 = As[ty*4+0][kk], a1 = As[ty*4+1][kk], a2 = As[ty*4+2][kk], a3 = As[ty*4+3][kk];
      float b0 = Bs[tx*4+0][kk], b1 = Bs[tx*4+1][kk], b2 = Bs[tx*4+2][kk], b3 = Bs[tx*4+3][kk];
      acc[0][0]=fmaf(a0,b0,acc[0][0]); acc[0][1]=fmaf(a0,b1,acc[0][1]); acc[0][2]=fmaf(a0,b2,acc[0][2]); acc[0][3]=fmaf(a0,b3,acc[0][3]);
      acc[1][0]=fmaf(a1,b0,acc[1][0]); acc[1][1]=fmaf(a1,b1,acc[1][1]); acc[1][2]=fmaf(a1,b2,acc[1][2]); acc[1][3]=fmaf(a1,b3,acc[1][3]);
      acc[2][0]=fmaf(a2,b0,acc[2][0]); acc[2][1]=fmaf(a2,b1,acc[2][1]); acc[2][2]=fmaf(a2,b2,acc[2][2]); acc[2][3]=fmaf(a2,b3,acc[2][3]);
      acc[3][0]=fmaf(a3,b0,acc[3][0]); acc[3][1]=fmaf(a3,b1,acc[3][1]); acc[3][2]=fmaf(a3,b2,acc[3][2]); acc[3][3]=fmaf(a3,b3,acc[3][3]);
    }
    __syncthreads();
  }
  #pragma unroll
  for (int i = 0; i < 4; ++i)
    #pragma unroll
    for (int j = 0; j < 4; ++j) {
      const int m = bm + ty*4 + i, n = bn + tx*4 + j;
      if (m < M && n < N) {
        float v = acc[i][j] + (bias ? bias[n] : 0.f);
        if (act == 1) v = fmaxf(v, 0.f);
        C[(size_t)m * ldc + n] = v;
      }
    }
}

// ---------------- persistent recurrence: 128 WGs x 512 thr, 1-wave polling ----------------
// WG wg owns nh cols [8wg, 8wg+8). Waves 0-5: 4 gate-rows each (idx=wv*4+q;
// part=idx>>3, col=idx&7) of the active matrix, streamed from L2 each stage.
// Wave 6: w rows 4wg,4wg+1 (S1) + Wh rows 2wg,2wg+1 (S3/S4 -> e0p/e1p).
// Wave 7: w rows 4wg+2,4wg+3 (S1) + Wac rows 2wg,2wg+1 (S3/S4 -> u0/u1) + sum(w) (S2).
// ONLY WAVE 0 POLLS; results broadcast through LDS.
__global__ __launch_bounds__(NT) void k_recur(
    float* __restrict__ ws,
    const float* __restrict__ Whh0, const float* __restrict__ bhh0,
    const float* __restrict__ Wih1, const float* __restrict__ bih1,
    const float* __restrict__ Whh1, const float* __restrict__ bhh1,
    const float* __restrict__ Wh,   const float* __restrict__ bh,
    const float* __restrict__ vh,   const float* __restrict__ vhb,
    const float* __restrict__ va,   const float* __restrict__ vab,
    const float* __restrict__ Wac)
{
  const float* Genc  = ws + WS_GENC;
  const float* gitok = ws + WS_GITOK;
  const float* Ex    = ws + WS_EX;
  float* H1 = ws + WS_H1;
  u64* TG   = (u64*)(ws + WS_TAGF);
  u64* tNH0 = TG + TG_NH0;
  u64* tNH1 = TG + TG_NH1;
  u64* tW   = TG + TG_W;
  u64* tEU  = TG + TG_EU;

  const int wg = blockIdx.x, tid = threadIdx.x;
  const int lane = tid & 63, wv = tid >> 6;

  __shared__ float xva[HID];     // nh0 / h0n staging
  __shared__ float xvb[HID];     // nh1 staging
  __shared__ float wl[S_LEN];
  __shared__ float cb[AD];
  __shared__ float u0l[AD], u1l[AD];
  __shared__ float e0l[NWG], e1l[NWG];
  __shared__ float sgh0[24], sacc[24], gh1l[24], b0l[24], bi1l[24], bh1l[24];
  __shared__ float sred[4];

  // biases -> LDS (once)
  if (tid < 24) {
    const int part = tid >> 3, cl = tid & 7;
    const int r = part * HID + wg * 8 + cl;
    b0l[tid]  = bhh0[r];
    bi1l[tid] = bih1[r];
    const float bb = bhh1[r];
    bh1l[tid] = bb;
    gh1l[tid] = bb;                 // gh1(t=0) = Whh1@0 + bhh1
  }
  // persistent small registers for waves 6,7
  float4 exr0 = {0,0,0,0}, exr1 = {0,0,0,0}, var = {0,0,0,0};
  float vh0 = 0.f, vh1 = 0.f, bhv0 = 0.f, bhv1 = 0.f;
  if (wv >= 6) {
    const int s0 = 4 * wg + 2 * (wv - 6);
    exr0 = ((const float4*)(Ex + (size_t)s0 * AD))[lane];
    exr1 = ((const float4*)(Ex + (size_t)(s0 + 1) * AD))[lane];
    var  = ((const float4*)va)[lane];
    vh0 = vh[2 * wg]; vh1 = vh[2 * wg + 1];
    bhv0 = bh[2 * wg]; bhv1 = bh[2 * wg + 1];
  }
  const float vabv = vab[0], vhb0 = vhb[0];

  xva[tid] = 0.f; xva[tid + 512] = 0.f;
  xvb[tid] = 0.f; xvb[tid + 512] = 0.f;
  __syncthreads();

  const float4* XA4 = (const float4*)xva;
  const float4* XB4 = (const float4*)xvb;
  const float4* WL4 = (const float4*)wl;

  #pragma unroll 1
  for (int t = 0; t < T_LEN; ++t) {
    const int c = t & 1, pc = c ^ 1;
    const unsigned tg = (unsigned)(t + 1);
    const unsigned tp = (unsigned)t;

    // ===== S1: gather e/u (wave0); alpha; h0n; c; gh0; publish w =====
    {
      float4 wr[4][4];
      if (wv < 6) {
        #pragma unroll
        for (int q = 0; q < 4; ++q) {
          const int idx = wv * 4 + q;
          const float4* Wp = (const float4*)(Whh0 + (size_t)((idx >> 3) * HID + wg * 8 + (idx & 7)) * HID);
          #pragma unroll
          for (int p = 0; p < 4; ++p) wr[q][p] = Wp[p * 64 + lane];
        }
      }
      if (wv == 0) {
        const u64* L0 = tEU + ((size_t)pc * NWG + 2 * lane) * 8;
        const u64* L1 = L0 + 8;
        u64 a0,a1,a2,a3,a4,a5, d0,d1,d2,d3,d4,d5;
        for (;;) {
          a0=ald(L0+0); a1=ald(L0+1); a2=ald(L0+2); a3=ald(L0+3); a4=ald(L0+4); a5=ald(L0+5);
          d0=ald(L1+0); d1=ald(L1+1); d2=ald(L1+2); d3=ald(L1+3); d4=ald(L1+4); d5=ald(L1+5);
          if (TAGOK(a0,tp)&TAGOK(a1,tp)&TAGOK(a2,tp)&TAGOK(a3,tp)&TAGOK(a4,tp)&TAGOK(a5,tp)&
              TAGOK(d0,tp)&TAGOK(d1,tp)&TAGOK(d2,tp)&TAGOK(d3,tp)&TAGOK(d4,tp)&TAGOK(d5,tp)) break;
          __builtin_amdgcn_s_sleep(2);
        }
        const int i0 = 2 * lane, i1 = 2 * lane + 1;
        e0l[i0] = LO_F(a0); u0l[2*i0] = LO_F(a1); u0l[2*i0+1] = LO_F(a2);
        e1l[i0] = LO_F(a3); u1l[2*i0] = LO_F(a4); u1l[2*i0+1] = LO_F(a5);
        e0l[i1] = LO_F(d0); u0l[2*i1] = LO_F(d1); u0l[2*i1+1] = LO_F(d2);
        e1l[i1] = LO_F(d3); u1l[2*i1] = LO_F(d4); u1l[2*i1+1] = LO_F(d5);
      }
      __syncthreads();
      if (wv == 0)      { float a = e0l[lane] + e0l[64 + lane]; a = wred64(a); if (lane == 0) sred[0] = a; }
      else if (wv == 1) { float a = e1l[lane] + e1l[64 + lane]; a = wred64(a); if (lane == 0) sred[1] = a; }
      __syncthreads();
      const float ea = __expf(sred[0] + vhb0), eb = __expf(sred[1] + vhb0);
      const float rs = 1.f / (ea + eb);
      const float al0 = ea * rs, al1 = eb * rs;
      {
        const float h0 = al0 * xva[tid]       + al1 * xvb[tid];
        const float h1 = al0 * xva[tid + 512] + al1 * xvb[tid + 512];
        xva[tid] = h0; xva[tid + 512] = h1;
      }
      if (tid < AD) cb[tid] = al0 * u0l[tid] + al1 * u1l[tid];
      __syncthreads();
      if (wv < 6) {
        const float4 x0 = XA4[lane], x1 = XA4[64+lane], x2 = XA4[128+lane], x3 = XA4[192+lane];
        #pragma unroll
        for (int q = 0; q < 4; ++q) {
          float a = qdot4(wr[q][0], wr[q][1], wr[q][2], wr[q][3], x0, x1, x2, x3);
          a = wred64(a);
          if (lane == 0) sgh0[wv * 4 + q] = a + b0l[wv * 4 + q];
        }
      } else {
        const float4 c4 = ((const float4*)cb)[lane];
        float s0 = var.x * fast_tanh(exr0.x + c4.x) + var.y * fast_tanh(exr0.y + c4.y)
                 + var.z * fast_tanh(exr0.z + c4.z) + var.w * fast_tanh(exr0.w + c4.w);
        float s1 = var.x * fast_tanh(exr1.x + c4.x) + var.y * fast_tanh(exr1.y + c4.y)
                 + var.z * fast_tanh(exr1.z + c4.z) + var.w * fast_tanh(exr1.w + c4.w);
        s0 = wred64(s0); s1 = wred64(s1);
        if (lane == 0) {
          u64* LWl = tW + ((size_t)c * NWG + wg) * 8 + 2 * (wv - 6);
          stq(LWl + 0, __expf(s0 + vabv), tg);
          stq(LWl + 1, __expf(s1 + vabv), tg);
        }
      }
    }

    // ===== S2: gather w (wave0); sum; Genc@w; GRU0 combine; publish nh0 =====
    {
      float4 gr[4][2];
      if (wv < 6) {
        #pragma unroll
        for (int q = 0; q < 4; ++q) {
          const int idx = wv * 4 + q;
          const float4* Gp = (const float4*)(Genc + (size_t)((idx >> 3) * HID + wg * 8 + (idx & 7)) * S_LEN);
          gr[q][0] = Gp[lane]; gr[q][1] = Gp[64 + lane];
        }
      }
      float g0 = 0.f, g1 = 0.f, g2 = 0.f;
      if (tid < 8) {
        const float* gp = gitok + (size_t)t * G3 + wg * 8 + tid;
        g0 = gp[0]; g1 = gp[HID]; g2 = gp[2 * HID];
      }
      if (wv == 0) {
        const u64* L0 = tW + ((size_t)c * NWG + 2 * lane) * 8;
        const u64* L1 = L0 + 8;
        u64 a0,a1,a2,a3, d0,d1,d2,d3;
        for (;;) {
          a0=ald(L0+0); a1=ald(L0+1); a2=ald(L0+2); a3=ald(L0+3);
          d0=ald(L1+0); d1=ald(L1+1); d2=ald(L1+2); d3=ald(L1+3);
          if (TAGOK(a0,tg)&TAGOK(a1,tg)&TAGOK(a2,tg)&TAGOK(a3,tg)&
              TAGOK(d0,tg)&TAGOK(d1,tg)&TAGOK(d2,tg)&TAGOK(d3,tg)) break;
          __builtin_amdgcn_s_sleep(2);
        }
        wl[8*lane+0] = LO_F(a0); wl[8*lane+1] = LO_F(a1); wl[8*lane+2] = LO_F(a2); wl[8*lane+3] = LO_F(a3);
        wl[8*lane+4] = LO_F(d0); wl[8*lane+5] = LO_F(d1); wl[8*lane+6] = LO_F(d2); wl[8*lane+7] = LO_F(d3);
      }
      __syncthreads();
      if (wv == 7) {
        float s = 0.f;
        #pragma unroll
        for (int k = 0; k < 8; ++k) s += wl[lane + 64 * k];
        s = wred64(s);
        if (lane == 0) sred[2] = s;
      }
      if (wv < 6) {
        const float4 w0 = WL4[lane], w1 = WL4[64 + lane];
        #pragma unroll
        for (int q = 0; q < 4; ++q) {
          float a = qdot2(gr[q][0], gr[q][1], w0, w1);
          a = wred64(a);
          if (lane == 0) sacc[wv * 4 + q] = a;
        }
      }
      __syncthreads();
      if (tid < 8) {
        const float inv = 1.f / sred[2];
        const float d0 = sacc[tid]      * inv + g0;
        const float d1 = sacc[8 + tid]  * inv + g1;
        const float d2 = sacc[16 + tid] * inv + g2;
        const float rg = fast_sigmoid(d0 + sgh0[tid]);
        const float zg = fast_sigmoid(d1 + sgh0[8 + tid]);
        const float ng = fast_tanh(d2 + rg * sgh0[16 + tid]);
        const float nv = (1.f - zg) * ng + zg * xva[wg * 8 + tid];
        stq(tNH0 + ((size_t)c * NWG + wg) * 8 + tid, nv, tg);
      }
    }

    // ===== S3: gather nh0 (wave0); Wih1 gates; e0p/u0; GRU1 combine; publish nh1 =====
    float4 whA[4], whB[4];     // wave6: Wh rows; wave7: Wac rows (reused in S4)
    {
      float4 wr[4][4];
      if (wv < 6) {
        #pragma unroll
        for (int q = 0; q < 4; ++q) {
          const int idx = wv * 4 + q;
          const float4* Wp = (const float4*)(Wih1 + (size_t)((idx >> 3) * HID + wg * 8 + (idx & 7)) * HID);
          #pragma unroll
          for (int p = 0; p < 4; ++p) wr[q][p] = Wp[p * 64 + lane];
        }
      } else {
        const float* M = (wv == 6) ? Wh : Wac;
        const float4* P0 = (const float4*)(M + (size_t)(2 * wg) * HID);
        const float4* P1 = (const float4*)(M + (size_t)(2 * wg + 1) * HID);
        #pragma unroll
        for (int p = 0; p < 4; ++p) { whA[p] = P0[p * 64 + lane]; whB[p] = P1[p * 64 + lane]; }
      }
      if (wv == 0) {
        const u64* L0 = tNH0 + ((size_t)c * NWG + 2 * lane) * 8;
        const u64* L1 = L0 + 8;
        u64 a0,a1,a2,a3,a4,a5,a6,a7, d0,d1,d2,d3,d4,d5,d6,d7;
        for (;;) {
          a0=ald(L0+0); a1=ald(L0+1); a2=ald(L0+2); a3=ald(L0+3);
          a4=ald(L0+4); a5=ald(L0+5); a6=ald(L0+6); a7=ald(L0+7);
          d0=ald(L1+0); d1=ald(L1+1); d2=ald(L1+2); d3=ald(L1+3);
          d4=ald(L1+4); d5=ald(L1+5); d6=ald(L1+6); d7=ald(L1+7);
          if (TAGOK(a0,tg)&TAGOK(a1,tg)&TAGOK(a2,tg)&TAGOK(a3,tg)&
              TAGOK(a4,tg)&TAGOK(a5,tg)&TAGOK(a6,tg)&TAGOK(a7,tg)&
              TAGOK(d0,tg)&TAGOK(d1,tg)&TAGOK(d2,tg)&TAGOK(d3,tg)&
              TAGOK(d4,tg)&TAGOK(d5,tg)&TAGOK(d6,tg)&TAGOK(d7,tg)) break;
          __builtin_amdgcn_s_sleep(2);
        }
        const int b = 16 * lane;
        xva[b+0]=LO_F(a0); xva[b+1]=LO_F(a1); xva[b+2]=LO_F(a2); xva[b+3]=LO_F(a3);
        xva[b+4]=LO_F(a4); xva[b+5]=LO_F(a5); xva[b+6]=LO_F(a6); xva[b+7]=LO_F(a7);
        xva[b+8]=LO_F(d0); xva[b+9]=LO_F(d1); xva[b+10]=LO_F(d2); xva[b+11]=LO_F(d3);
        xva[b+12]=LO_F(d4); xva[b+13]=LO_F(d5); xva[b+14]=LO_F(d6); xva[b+15]=LO_F(d7);
      }
      __syncthreads();
      const float4 y0 = XA4[lane], y1 = XA4[64+lane], y2 = XA4[128+lane], y3 = XA4[192+lane];
      if (wv < 6) {
        #pragma unroll
        for (int q = 0; q < 4; ++q) {
          float a = qdot4(wr[q][0], wr[q][1], wr[q][2], wr[q][3], y0, y1, y2, y3);
          a = wred64(a);
          if (lane == 0) sacc[wv * 4 + q] = a;
        }
      } else if (wv == 6) {
        float a0 = wred64(qdot4(whA[0], whA[1], whA[2], whA[3], y0, y1, y2, y3));
        float a1 = wred64(qdot4(whB[0], whB[1], whB[2], whB[3], y0, y1, y2, y3));
        if (lane == 0)
          stq(tEU + ((size_t)c * NWG + wg) * 8 + 0,
              vh0 * fast_tanh(a0 + bhv0) + vh1 * fast_tanh(a1 + bhv1), tg);
      } else {
        float a0 = wred64(qdot4(whA[0], whA[1], whA[2], whA[3], y0, y1, y2, y3));
        float a1 = wred64(qdot4(whB[0], whB[1], whB[2], whB[3], y0, y1, y2, y3));
        if (lane == 0) {
          stq(tEU + ((size_t)c * NWG + wg) * 8 + 1, a0, tg);
          stq(tEU + ((size_t)c * NWG + wg) * 8 + 2, a1, tg);
        }
      }
      __syncthreads();
      if (tid < 8) {
        const float rg = fast_sigmoid(sacc[tid]      + bi1l[tid]      + gh1l[tid]);
        const float zg = fast_sigmoid(sacc[8 + tid]  + bi1l[8 + tid]  + gh1l[8 + tid]);
        const float ng = fast_tanh(sacc[16 + tid] + bi1l[16 + tid] + rg * gh1l[16 + tid]);
        const float nv = (1.f - zg) * ng + zg * xvb[wg * 8 + tid];
        stq(tNH1 + ((size_t)c * NWG + wg) * 8 + tid, nv, tg);
        H1[(size_t)t * HID + wg * 8 + tid] = nv;
      }
    }

    // ===== S4: gather nh1 (wave0); gh1_next; e1p/u1 =====
    {
      float4 wr[4][4];
      if (wv < 6) {
        #pragma unroll
        for (int q = 0; q < 4; ++q) {
          const int idx = wv * 4 + q;
          const float4* Wp = (const float4*)(Whh1 + (size_t)((idx >> 3) * HID + wg * 8 + (idx & 7)) * HID);
          #pragma unroll
          for (int p = 0; p < 4; ++p) wr[q][p] = Wp[p * 64 + lane];
        }
      }
      if (wv == 0) {
        const u64* L0 = tNH1 + ((size_t)c * NWG + 2 * lane) * 8;
        const u64* L1 = L0 + 8;
        u64 a0,a1,a2,a3,a4,a5,a6,a7, d0,d1,d2,d3,d4,d5,d6,d7;
        for (;;) {
          a0=ald(L0+0); a1=ald(L0+1); a2=ald(L0+2); a3=ald(L0+3);
          a4=ald(L0+4); a5=ald(L0+5); a6=ald(L0+6); a7=ald(L0+7);
          d0=ald(L1+0); d1=ald(L1+1); d2=ald(L1+2); d3=ald(L1+3);
          d4=ald(L1+4); d5=ald(L1+5); d6=ald(L1+6); d7=ald(L1+7);
          if (TAGOK(a0,tg)&TAGOK(a1,tg)&TAGOK(a2,tg)&TAGOK(a3,tg)&
              TAGOK(a4,tg)&TAGOK(a5,tg)&TAGOK(a6,tg)&TAGOK(a7,tg)&
              TAGOK(d0,tg)&TAGOK(d1,tg)&TAGOK(d2,tg)&TAGOK(d3,tg)&
              TAGOK(d4,tg)&TAGOK(d5,tg)&TAGOK(d6,tg)&TAGOK(d7,tg)) break;
          __builtin_amdgcn_s_sleep(2);
        }
        const int b = 16 * lane;
        xvb[b+0]=LO_F(a0); xvb[b+1]=LO_F(a1); xvb[b+2]=LO_F(a2); xvb[b+3]=LO_F(a3);
        xvb[b+4]=LO_F(a4); xvb[b+5]=LO_F(a5); xvb[b+6]=LO_F(a6); xvb[b+7]=LO_F(a7);
        xvb[b+8]=LO_F(d0); xvb[b+9]=LO_F(d1); xvb[b+10]=LO_F(d2); xvb[b+11]=LO_F(d3);
        xvb[b+12]=LO_F(d4); xvb[b+13]=LO_F(d5); xvb[b+14]=LO_F(d6); xvb[b+15]=LO_F(d7);
      }
      __syncthreads();
      const float4 y0 = XB4[lane], y1 = XB4[64+lane], y2 = XB4[128+lane], y3 = XB4[192+lane];
      if (wv < 6) {
        #pragma unroll
        for (int q = 0; q < 4; ++q) {
          float a = qdot4(wr[q][0], wr[q][1], wr[q][2], wr[q][3], y0, y1, y2, y3);
          a = wred64(a);
          if (lane == 0) gh1l[wv * 4 + q] = a + bh1l[wv * 4 + q];
        }
      } else if (wv == 6) {
        float a0 = wred64(qdot4(whA[0], whA[1], whA[2], whA[3], y0, y1, y2, y3));
        float a1 = wred64(qdot4(whB[0], whB[1], whB[2], whB[3], y0, y1, y2, y3));
        if (lane == 0)
          stq(tEU + ((size_t)c * NWG + wg) * 8 + 3,
              vh0 * fast_tanh(a0 + bhv0) + vh1 * fast_tanh(a1 + bhv1), tg);
      } else {
        float a0 = wred64(qdot4(whA[0], whA[1], whA[2], whA[3], y0, y1, y2, y3));
        float a1 = wred64(qdot4(whB[0], whB[1], whB[2], whB[3], y0, y1, y2, y3));
        if (lane == 0) {
          stq(tEU + ((size_t)c * NWG + wg) * 8 + 4, a0, tg);
          stq(tEU + ((size_t)c * NWG + wg) * 8 + 5, a1, tg);
        }
      }
    }
  }
}

// ---------------- output head ----------------
__global__ __launch_bounds__(256) void k_head(
    const float* __restrict__ FC1, const float* __restrict__ Wf2,
    const float* __restrict__ bf2, float* __restrict__ out, float* __restrict__ rowp)
{
  __shared__ float fcb[256 * 32];
  const int v = blockIdx.x * 256 + threadIdx.x;
  const bool ok = v < VOC;
  float wf[32];
  float bb = 0.f;
  if (ok) {
    const float4* W4 = (const float4*)(Wf2 + (size_t)v * 32);
    #pragma unroll
    for (int q = 0; q < 8; ++q) ((float4*)wf)[q] = W4[q];
    bb = bf2[v];
  }
  const int wv = threadIdx.x >> 6;
  #pragma unroll 1
  for (int half = 0; half < 2; ++half) {
    __syncthreads();
    for (int i = threadIdx.x; i < 256 * 32 / 4; i += 256)
      ((float4*)fcb)[i] = ((const float4*)(FC1 + half * 256 * 32))[i];
    __syncthreads();
    #pragma unroll 1
    for (int tt = 0; tt < 256; ++tt) {
      const int t = half * 256 + tt;
      const float4* f4 = (const float4*)(fcb + tt * 32);
      float acc = bb;
      #pragma unroll
      for (int q = 0; q < 8; ++q) {
        float4 f = f4[q];
        acc = fmaf(wf[4*q+0], f.x, acc);
        acc = fmaf(wf[4*q+1], f.y, acc);
        acc = fmaf(wf[4*q+2], f.z, acc);
        acc = fmaf(wf[4*q+3], f.w, acc);
      }
      const float w = ok ? __expf(acc) : 0.f;
      if (ok) out[(size_t)t * VOC + v] = w;
      float r = wred64(w);
      if ((threadIdx.x & 63) == 0)
        rowp[(size_t)t * NPART + (size_t)blockIdx.x * 4 + wv] = r;
    }
  }
}

__global__ __launch_bounds__(256) void k_rowsum(const float* __restrict__ rowp, float* __restrict__ inv) {
  const int t = blockIdx.x;
  float acc = 0.f;
  for (int i = threadIdx.x; i < NPART; i += 256) acc += rowp[(size_t)t * NPART + i];
  acc = wred64(acc);
  __shared__ float sr[4];
  if ((threadIdx.x & 63) == 0) sr[threadIdx.x >> 6] = acc;
  __syncthreads();
  if (threadIdx.x == 0) inv[t] = 1.f / (sr[0] + sr[1] + sr[2] + sr[3]);
}

__global__ __launch_bounds__(256) void k_scale(float* __restrict__ out, const float* __restrict__ inv) {
  const int t = blockIdx.y;
  const float s = inv[t];
  const size_t base = (size_t)t * VOC;
  const int v0 = blockIdx.x * 2048 + threadIdx.x;
  #pragma unroll
  for (int k = 0; k < 8; ++k) {
    const int v = v0 + k * 256;
    if (v < VOC) out[base + v] *= s;
  }
}

extern "C" void kernel_launch(void* const* d_in, const int* in_sizes, int n_in,
                              void* d_out, int out_size, void* d_ws, size_t ws_size,
                              hipStream_t stream) {
  const int*   dec  = (const int*)  d_in[0];
  const float* enc  = (const float*)d_in[1];
  const float* emb  = (const float*)d_in[2];
  const float* Wax  = (const float*)d_in[3];
  const float* Wac  = (const float*)d_in[4];
  const float* ba   = (const float*)d_in[5];
  const float* va   = (const float*)d_in[6];
  const float* vab  = (const float*)d_in[7];
  const float* Wih0 = (const float*)d_in[8];
  const float* bih0 = (const float*)d_in[9];
  const float* Whh0 = (const float*)d_in[10];
  const float* bhh0 = (const float*)d_in[11];
  const float* Wih1 = (const float*)d_in[12];
  const float* bih1 = (const float*)d_in[13];
  const float* Whh1 = (const float*)d_in[14];
  const float* bhh1 = (const float*)d_in[15];
  const float* Wh   = (const float*)d_in[16];
  const float* bh   = (const float*)d_in[17];
  const float* vh   = (const float*)d_in[18];
  const float* vhb  = (const float*)d_in[19];
  const float* Wf1  = (const float*)d_in[20];
  const float* bf1  = (const float*)d_in[21];
  const float* Wf2  = (const float*)d_in[22];
  const float* bf2  = (const float*)d_in[23];
  float* out = (float*)d_out;
  float* ws  = (float*)d_ws;

  k_init<<<32, 256, 0, stream>>>(ws);   // 32*256 == TG_TOT

  // Genc[r][s] = Wih0[r, :1024] . enc[s]          (M=3072, N=512)
  k_gemm<<<dim3(8, 48), 256, 0, stream>>>(Wih0, 2048, nullptr, enc, 1024, 0,
                                          nullptr, ws + WS_GENC, 512, G3, S_LEN, 0);
  // gi_tok[t][r] = emb[dec[t]] . Wih0[r, 1024:] + bih0[r]   (M=512, N=3072)
  k_gemm<<<dim3(48, 8), 256, 0, stream>>>(emb, 1024, dec, Wih0, 2048, 1024,
                                          bih0, ws + WS_GITOK, G3, T_LEN, G3, 0);
  // Ex[s][i] = enc[s] . Wa_x[i] + ba[i]           (M=512, N=256)
  k_gemm<<<dim3(4, 8), 256, 0, stream>>>(enc, 1024, nullptr, Wax, 1024, 0,
                                         ba, ws + WS_EX, AD, S_LEN, AD, 0);

  k_recur<<<NWG, NT, 0, stream>>>(ws, Whh0, bhh0, Wih1, bih1, Whh1, bhh1,
                                  Wh, bh, vh, vhb, va, vab, Wac);

  // FC1[t] = relu(Wf1 @ H1[t] + bf1)              (M=512, N=32)
  k_gemm<<<dim3(1, 8), 256, 0, stream>>>(ws + WS_H1, 1024, nullptr, Wf1, 1024, 0,
                                         bf1, ws + WS_FC1, 32, T_LEN, 32, 1);

  k_head<<<197, 256, 0, stream>>>(ws + WS_FC1, Wf2, bf2, out, ws + WS_ROWP);
  k_rowsum<<<512, 256, 0, stream>>>(ws + WS_ROWP, ws + WS_INV);
  k_scale<<<dim3(25, 512), 256, 0, stream>>>(out, ws + WS_INV);
}

// Round 8
// 7442.410 us; speedup vs baseline: 1.8411x; 1.8411x over previous
//
#include <hip/hip_runtime.h>
#include <cstdint>
#include <cstddef>

#define T_LEN 512
#define S_LEN 512
#define HID   1024
#define AD    256
#define VOC   50257
#define G3    3072
#define NWG   256
#define NT    512
#define NPART (197*4)

typedef unsigned long long u64;

// ---------------- workspace layout (float offsets) ----------------
#define WS_GENC   0
#define WS_GITOK  (WS_GENC + G3*S_LEN)
#define WS_EX     (WS_GITOK + T_LEN*G3)
#define WS_H1     (WS_EX + S_LEN*AD)
#define WS_FC1    (WS_H1 + T_LEN*HID)
#define WS_ROWP   (WS_FC1 + T_LEN*32)
#define WS_INV    (WS_ROWP + T_LEN*NPART)
#define WS_TAGF   (((WS_INV + T_LEN) + 15) & ~15)   // 64B-aligned

// ---- tagged dataflow: ONE 64B line (8 u64) per producer WG per class ----
// EU[c][p]  = {e0p, e1p, u0, u1}   (e0p,u0 published at S3; e1p,u1 at S4)
// W [c][p]  = {w[2p], w[2p+1]}
// NH0[c][p] = {nh0[4p..4p+3]} ; NH1 same
#define TG_EU  0
#define TG_W   (TG_EU  + 2*NWG*8)
#define TG_NH0 (TG_W   + 2*NWG*8)
#define TG_NH1 (TG_NH0 + 2*NWG*8)
#define TG_TOT (TG_NH1 + 2*NWG*8)                    // 16384 u64 = 128KB

__device__ inline float wred64(float v) {
  v += __shfl_xor(v, 32, 64); v += __shfl_xor(v, 16, 64); v += __shfl_xor(v, 8, 64);
  v += __shfl_xor(v, 4, 64);  v += __shfl_xor(v, 2, 64);  v += __shfl_xor(v, 1, 64);
  return v;
}
__device__ inline float fast_sigmoid(float x) { return 1.f / (1.f + __expf(-x)); }
__device__ inline float fast_tanh(float x) {
  float e = __expf(2.f * x);
  return 1.f - 2.f / (e + 1.f);
}

__device__ inline u64 ald(const u64* p) {
  return __hip_atomic_load(p, __ATOMIC_RELAXED, __HIP_MEMORY_SCOPE_AGENT);
}
__device__ inline void stq(u64* p, float v, unsigned tag) {
  __hip_atomic_store(p, ((u64)tag << 32) | (u64)__float_as_uint(v),
                     __ATOMIC_RELAXED, __HIP_MEMORY_SCOPE_AGENT);
}
#define LO_F(x) __uint_as_float((unsigned)(x))
#define TAGOK(x, t) (((unsigned)((x) >> 32)) == (t))

__device__ inline float qdot4(const float4& a0, const float4& a1, const float4& a2, const float4& a3,
                              const float4& x0, const float4& x1, const float4& x2, const float4& x3) {
  float a = 0.f;
  a = fmaf(a0.x, x0.x, a); a = fmaf(a0.y, x0.y, a); a = fmaf(a0.z, x0.z, a); a = fmaf(a0.w, x0.w, a);
  a = fmaf(a1.x, x1.x, a); a = fmaf(a1.y, x1.y, a); a = fmaf(a1.z, x1.z, a); a = fmaf(a1.w, x1.w, a);
  a = fmaf(a2.x, x2.x, a); a = fmaf(a2.y, x2.y, a); a = fmaf(a2.z, x2.z, a); a = fmaf(a2.w, x2.w, a);
  a = fmaf(a3.x, x3.x, a); a = fmaf(a3.y, x3.y, a); a = fmaf(a3.z, x3.z, a); a = fmaf(a3.w, x3.w, a);
  return a;
}
__device__ inline float qdot2(const float4& a0, const float4& a1,
                              const float4& x0, const float4& x1) {
  float a = 0.f;
  a = fmaf(a0.x, x0.x, a); a = fmaf(a0.y, x0.y, a); a = fmaf(a0.z, x0.z, a); a = fmaf(a0.w, x0.w, a);
  a = fmaf(a1.x, x1.x, a); a = fmaf(a1.y, x1.y, a); a = fmaf(a1.z, x1.z, a); a = fmaf(a1.w, x1.w, a);
  return a;
}

// ---------------- init: zero all tag words (tag 0 == initial zero state) ----------------
__global__ void k_init(float* ws) {
  u64* TG = (u64*)(ws + WS_TAGF);
  const int i = blockIdx.x * 256 + threadIdx.x;
  if (i < TG_TOT) TG[i] = 0ull;
}

// ---------------- generic tiled fp32 GEMM (pre/post passes) ----------------
__global__ __launch_bounds__(256) void k_gemm(
    const float* __restrict__ A, int lda, const int* __restrict__ gidx,
    const float* __restrict__ B, int ldb, int kofs,
    const float* __restrict__ bias, float* __restrict__ C, int ldc,
    int M, int N, int act)
{
  __shared__ float As[64][33];
  __shared__ float Bs[64][33];
  const int bm = blockIdx.y * 64, bn = blockIdx.x * 64;
  const int tx = threadIdx.x & 15, ty = threadIdx.x >> 4;
  float acc[4][4] = {};
  const int lin = threadIdx.x * 8;
  const int lr = lin >> 5;
  const int lc = lin & 31;
  for (int k0 = 0; k0 < 1024; k0 += 32) {
    {
      const int gm = bm + lr;
      float4 v0 = {0,0,0,0}, v1 = {0,0,0,0};
      if (gm < M) {
        const int row = gidx ? gidx[gm] : gm;
        const float* p = A + (size_t)row * lda + k0 + lc;
        v0 = *(const float4*)p; v1 = *(const float4*)(p + 4);
      }
      As[lr][lc+0]=v0.x; As[lr][lc+1]=v0.y; As[lr][lc+2]=v0.z; As[lr][lc+3]=v0.w;
      As[lr][lc+4]=v1.x; As[lr][lc+5]=v1.y; As[lr][lc+6]=v1.z; As[lr][lc+7]=v1.w;
    }
    {
      const int gn = bn + lr;
      float4 v0 = {0,0,0,0}, v1 = {0,0,0,0};
      if (gn < N) {
        const float* p = B + (size_t)gn * ldb + kofs + k0 + lc;
        v0 = *(const float4*)p; v1 = *(const float4*)(p + 4);
      }
      Bs[lr][lc+0]=v0.x; Bs[lr][lc+1]=v0.y; Bs[lr][lc+2]=v0.z; Bs[lr][lc+3]=v0.w;
      Bs[lr][lc+4]=v1.x; Bs[lr][lc+5]=v1.y; Bs[lr][lc+6]=v1.z; Bs[lr][lc+7]=v1.w;
    }
    __syncthreads();
    #pragma unroll
    for (int kk = 0; kk < 32; ++kk) {
      float a0 = As[ty*4+0][kk], a1 = As[ty*4+1][kk], a2 = As[ty*4+2][kk], a3 = As[ty*4+3][kk];
      float b0 = Bs[tx*4+0][kk], b1 = Bs[tx*4+1][kk], b2 = Bs[tx*4+2][kk], b3 = Bs[tx*4+3][kk];
      acc[0][0]=fmaf(a0,b0,acc[0][0]); acc[0][1]=fmaf(a0,b1,acc[0][1]); acc[0][2]=fmaf(a0,b2,acc[0][2]); acc[0][3]=fmaf(a0,b3,acc[0][3]);
      acc[1][0]=fmaf(a1,b0,acc[1][0]); acc[1][1]=fmaf(a1,b1,acc[1][1]); acc[1][2]=fmaf(a1,b2,acc[1][2]); acc[1][3]=fmaf(a1,b3,acc[1][3]);
      acc[2][0]=fmaf(a2,b0,acc[2][0]); acc[2][1]=fmaf(a2,b1,acc[2][1]); acc[2][2]=fmaf(a2,b2,acc[2][2]); acc[2][3]=fmaf(a2,b3,acc[2][3]);
      acc[3][0]=fmaf(a3,b0,acc[3][0]); acc[3][1]=fmaf(a3,b1,acc[3][1]); acc[3][2]=fmaf(a3,b2,acc[3][2]); acc[3][3]=fmaf(a3,b3,acc[3][3]);
    }
    __syncthreads();
  }
  #pragma unroll
  for (int i = 0; i < 4; ++i)
    #pragma unroll
    for (int j = 0; j < 4; ++j) {
      const int m = bm + ty*4 + i, n = bn + tx*4 + j;
      if (m < M && n < N) {
        float v = acc[i][j] + (bias ? bias[n] : 0.f);
        if (act == 1) v = fmaxf(v, 0.f);
        C[(size_t)m * ldc + n] = v;
      }
    }
}

// ---------------- persistent recurrence: 256 WGs x 512 thr ----------------
// WG wg owns columns j in [4wg, 4wg+4). Waves 0-5 hold gate-rows lr=2wv,2wv+1
// (lr = gate*4 + col) of Whh0/Wih1/Whh1 (+2 Genc rows) in registers, loaded ONCE.
// Wave 6: Wh row wg + Ex row 2wg + va. Wave 7: Wac row wg + Ex row 2wg+1 + va.
// Communication: tagged 64B lines, polled ONLY by waves 0-3 (one line per lane),
// then LDS-broadcast. 4 one-round-trip hops per step, zero barriers.
__global__ __launch_bounds__(NT) void k_recur(
    float* __restrict__ ws,
    const float* __restrict__ Whh0, const float* __restrict__ bhh0,
    const float* __restrict__ Wih1, const float* __restrict__ bih1,
    const float* __restrict__ Whh1, const float* __restrict__ bhh1,
    const float* __restrict__ Wh,   const float* __restrict__ bh,
    const float* __restrict__ vh,   const float* __restrict__ vhb,
    const float* __restrict__ va,   const float* __restrict__ vab,
    const float* __restrict__ Wac)
{
  const float* Genc  = ws + WS_GENC;
  const float* gitok = ws + WS_GITOK;
  const float* Ex    = ws + WS_EX;
  float* H1 = ws + WS_H1;
  u64* TG   = (u64*)(ws + WS_TAGF);
  u64* tEU  = TG + TG_EU;
  u64* tW   = TG + TG_W;
  u64* tNH0 = TG + TG_NH0;
  u64* tNH1 = TG + TG_NH1;

  const int wg = blockIdx.x, tid = threadIdx.x;
  const int lane = tid & 63, wv = tid >> 6;

  __shared__ float xva[HID];     // nh0 copy; becomes h0n during S1/S2
  __shared__ float xvb[HID];     // nh1 copy
  __shared__ float wl[S_LEN];
  __shared__ float cb[AD];
  __shared__ float e0l[NWG], e1l[NWG], u0l[NWG], u1l[NWG];
  __shared__ float sgh0[12], sacc[12], gh1l[12], sb0[12], sbh1[12], sbi1[12];
  __shared__ float sred[4];

  // ---- persistent register-resident weights (r3 layout: declared once) ----
  float4 wreg[28];
  if (wv < 6) {
    #pragma unroll
    for (int r = 0; r < 2; ++r) {
      const int lr = 2 * wv + r;
      const int g = (lr >> 2) * HID + wg * 4 + (lr & 3);
      const float4* p0 = (const float4*)(Whh0 + (size_t)g * HID);
      const float4* p1 = (const float4*)(Wih1 + (size_t)g * HID);
      const float4* p2 = (const float4*)(Whh1 + (size_t)g * HID);
      const float4* pg = (const float4*)(Genc + (size_t)g * S_LEN);
      #pragma unroll
      for (int p = 0; p < 4; ++p) {
        wreg[r*4+p]      = p0[p*64 + lane];
        wreg[8 + r*4+p]  = p1[p*64 + lane];
        wreg[16 + r*4+p] = p2[p*64 + lane];
      }
      #pragma unroll
      for (int p = 0; p < 2; ++p) wreg[24 + r*2+p] = pg[p*64 + lane];
    }
  } else {
    const float* Wrow = (wv == 6) ? (Wh + (size_t)wg * HID) : (Wac + (size_t)wg * HID);
    const float4* p0 = (const float4*)Wrow;
    #pragma unroll
    for (int p = 0; p < 4; ++p) wreg[p] = p0[p*64 + lane];
    const int s = 2 * wg + (wv - 6);
    wreg[4] = ((const float4*)(Ex + (size_t)s * AD))[lane];
    wreg[5] = ((const float4*)va)[lane];
  }

  if (tid < 12) {
    const int g = (tid >> 2) * HID + wg * 4 + (tid & 3);
    sb0[tid]  = bhh0[g];
    sbi1[tid] = bih1[g];
    const float bb = bhh1[g];
    sbh1[tid] = bb;
    gh1l[tid] = bb;          // gh1(t=0) = Whh1@0 + bhh1
  }
  const float vhW = vh[wg], bhW = bh[wg];
  const float vabv = vab[0], vhb0 = vhb[0];

  xva[tid] = 0.f; xva[tid + 512] = 0.f;
  xvb[tid] = 0.f; xvb[tid + 512] = 0.f;
  __syncthreads();

  const float4* XA4 = (const float4*)xva;
  const float4* XB4 = (const float4*)xvb;
  const float4* WL4 = (const float4*)wl;
  const float4* CB4 = (const float4*)cb;

  #pragma unroll 1
  for (int t = 0; t < T_LEN; ++t) {
    const int c = t & 1, pc = c ^ 1;
    const unsigned tg = (unsigned)(t + 1);
    const unsigned tp = (unsigned)t;

    // ===== S1: gather EU (waves 0-3, 1 line/lane); alpha; h0n; c; gh0; publish w =====
    {
      if (wv < 4) {
        const int q = (wv << 6) | lane;
        const u64* L = tEU + ((size_t)pc * NWG + q) * 8;
        u64 x0, x1, x2, x3;
        for (;;) {
          x0 = ald(L); x1 = ald(L + 1); x2 = ald(L + 2); x3 = ald(L + 3);
          if (TAGOK(x0, tp) & TAGOK(x1, tp) & TAGOK(x2, tp) & TAGOK(x3, tp)) break;
          __builtin_amdgcn_s_sleep(1);
        }
        e0l[q] = LO_F(x0); e1l[q] = LO_F(x1); u0l[q] = LO_F(x2); u1l[q] = LO_F(x3);
      }
      __syncthreads();
      if (wv == 0) {
        float a = e0l[lane] + e0l[64 + lane] + e0l[128 + lane] + e0l[192 + lane];
        a = wred64(a);
        if (lane == 0) sred[0] = a;
      } else if (wv == 1) {
        float a = e1l[lane] + e1l[64 + lane] + e1l[128 + lane] + e1l[192 + lane];
        a = wred64(a);
        if (lane == 0) sred[1] = a;
      }
      __syncthreads();
      const float ea = __expf(sred[0] + vhb0), eb = __expf(sred[1] + vhb0);
      const float rs = 1.f / (ea + eb);
      const float al0 = ea * rs, al1 = eb * rs;
      {
        const float h0 = al0 * xva[tid]       + al1 * xvb[tid];
        const float h1 = al0 * xva[tid + 512] + al1 * xvb[tid + 512];
        xva[tid] = h0; xva[tid + 512] = h1;
      }
      if (tid < AD) cb[tid] = al0 * u0l[tid] + al1 * u1l[tid];
      __syncthreads();
      if (wv < 6) {
        const float4 x0 = XA4[lane], x1 = XA4[64+lane], x2 = XA4[128+lane], x3 = XA4[192+lane];
        float accA = qdot4(wreg[0], wreg[1], wreg[2], wreg[3], x0, x1, x2, x3);
        float accB = qdot4(wreg[4], wreg[5], wreg[6], wreg[7], x0, x1, x2, x3);
        accA = wred64(accA); accB = wred64(accB);
        if (lane == 0) {
          sgh0[2*wv]     = accA + sb0[2*wv];
          sgh0[2*wv + 1] = accB + sb0[2*wv + 1];
        }
      } else {
        const float4 e4 = wreg[4], v4 = wreg[5], c4 = CB4[lane];
        float acc = v4.x * fast_tanh(e4.x + c4.x) + v4.y * fast_tanh(e4.y + c4.y)
                  + v4.z * fast_tanh(e4.z + c4.z) + v4.w * fast_tanh(e4.w + c4.w);
        acc = wred64(acc);
        if (lane == 0)
          stq(tW + ((size_t)c * NWG + wg) * 8 + (wv - 6), __expf(acc + vabv), tg);
      }
    }

    // ===== S2: gather w (waves 0-3); sum(w); Genc@w; GRU0 combine; publish nh0 =====
    {
      float g0 = 0.f, g1 = 0.f, g2 = 0.f;
      if (tid < 4) {
        const float* gp = gitok + (size_t)t * G3 + wg * 4 + tid;
        g0 = gp[0]; g1 = gp[HID]; g2 = gp[2 * HID];
      }
      if (wv < 4) {
        const int q = (wv << 6) | lane;
        const u64* L = tW + ((size_t)c * NWG + q) * 8;
        u64 x0, x1;
        for (;;) {
          x0 = ald(L); x1 = ald(L + 1);
          if (TAGOK(x0, tg) & TAGOK(x1, tg)) break;
          __builtin_amdgcn_s_sleep(1);
        }
        wl[2*q] = LO_F(x0); wl[2*q + 1] = LO_F(x1);
      }
      __syncthreads();
      if (wv == 1) {
        float s = 0.f;
        #pragma unroll
        for (int k = 0; k < 8; ++k) s += wl[lane + 64 * k];
        s = wred64(s);
        if (lane == 0) sred[2] = s;
      }
      if (wv < 6) {
        const float4 w0 = WL4[lane], w1 = WL4[64 + lane];
        float accA = qdot2(wreg[24], wreg[25], w0, w1);
        float accB = qdot2(wreg[26], wreg[27], w0, w1);
        accA = wred64(accA); accB = wred64(accB);
        if (lane == 0) { sacc[2*wv] = accA; sacc[2*wv + 1] = accB; }
      }
      __syncthreads();
      if (tid < 4) {
        const float inv = 1.f / sred[2];
        const float d0 = sacc[tid]     * inv + g0;
        const float d1 = sacc[4 + tid] * inv + g1;
        const float d2 = sacc[8 + tid] * inv + g2;
        const float rg = fast_sigmoid(d0 + sgh0[tid]);
        const float zg = fast_sigmoid(d1 + sgh0[4 + tid]);
        const float ng = fast_tanh(d2 + rg * sgh0[8 + tid]);
        const float nv = (1.f - zg) * ng + zg * xva[wg * 4 + tid];
        stq(tNH0 + ((size_t)c * NWG + wg) * 8 + tid, nv, tg);
      }
    }

    // ===== S3: gather nh0 -> xva; Wih1 gates; e0p/u0 (early publish); GRU1; publish nh1 =====
    __syncthreads();   // protect xva (h0j reads done) before poll-writes
    {
      if (wv < 4) {
        const int q = (wv << 6) | lane;
        const u64* L = tNH0 + ((size_t)c * NWG + q) * 8;
        u64 x0, x1, x2, x3;
        for (;;) {
          x0 = ald(L); x1 = ald(L + 1); x2 = ald(L + 2); x3 = ald(L + 3);
          if (TAGOK(x0, tg) & TAGOK(x1, tg) & TAGOK(x2, tg) & TAGOK(x3, tg)) break;
          __builtin_amdgcn_s_sleep(1);
        }
        float4 v; v.x = LO_F(x0); v.y = LO_F(x1); v.z = LO_F(x2); v.w = LO_F(x3);
        ((float4*)xva)[q] = v;
      }
      __syncthreads();
      const float4 y0 = XA4[lane], y1 = XA4[64+lane], y2 = XA4[128+lane], y3 = XA4[192+lane];
      if (wv < 6) {
        float accA = qdot4(wreg[8],  wreg[9],  wreg[10], wreg[11], y0, y1, y2, y3);
        float accB = qdot4(wreg[12], wreg[13], wreg[14], wreg[15], y0, y1, y2, y3);
        accA = wred64(accA); accB = wred64(accB);
        if (lane == 0) { sacc[2*wv] = accA; sacc[2*wv + 1] = accB; }
      } else if (wv == 6) {
        float acc = wred64(qdot4(wreg[0], wreg[1], wreg[2], wreg[3], y0, y1, y2, y3));
        if (lane == 0)
          stq(tEU + ((size_t)c * NWG + wg) * 8 + 0, vhW * fast_tanh(acc + bhW), tg);
      } else {
        float acc = wred64(qdot4(wreg[0], wreg[1], wreg[2], wreg[3], y0, y1, y2, y3));
        if (lane == 0)
          stq(tEU + ((size_t)c * NWG + wg) * 8 + 2, acc, tg);
      }
      __syncthreads();
      if (tid < 4) {
        const float gr = sacc[tid]     + sbi1[tid];
        const float gz = sacc[4 + tid] + sbi1[4 + tid];
        const float gn = sacc[8 + tid] + sbi1[8 + tid];
        const float rg = fast_sigmoid(gr + gh1l[tid]);
        const float zg = fast_sigmoid(gz + gh1l[4 + tid]);
        const float ng = fast_tanh(gn + rg * gh1l[8 + tid]);
        const float nv = (1.f - zg) * ng + zg * xvb[wg * 4 + tid];
        stq(tNH1 + ((size_t)c * NWG + wg) * 8 + tid, nv, tg);
        H1[(size_t)t * HID + wg * 4 + tid] = nv;
      }
    }

    // ===== S4: gather nh1 -> xvb; gh1_next; e1p/u1 publish =====
    __syncthreads();   // protect xvb (oldn reads done) before poll-writes
    {
      if (wv < 4) {
        const int q = (wv << 6) | lane;
        const u64* L = tNH1 + ((size_t)c * NWG + q) * 8;
        u64 x0, x1, x2, x3;
        for (;;) {
          x0 = ald(L); x1 = ald(L + 1); x2 = ald(L + 2); x3 = ald(L + 3);
          if (TAGOK(x0, tg) & TAGOK(x1, tg) & TAGOK(x2, tg) & TAGOK(x3, tg)) break;
          __builtin_amdgcn_s_sleep(1);
        }
        float4 v; v.x = LO_F(x0); v.y = LO_F(x1); v.z = LO_F(x2); v.w = LO_F(x3);
        ((float4*)xvb)[q] = v;
      }
      __syncthreads();
      const float4 y0 = XB4[lane], y1 = XB4[64+lane], y2 = XB4[128+lane], y3 = XB4[192+lane];
      if (wv < 6) {
        float accA = qdot4(wreg[16], wreg[17], wreg[18], wreg[19], y0, y1, y2, y3);
        float accB = qdot4(wreg[20], wreg[21], wreg[22], wreg[23], y0, y1, y2, y3);
        accA = wred64(accA); accB = wred64(accB);
        if (lane == 0) {
          gh1l[2*wv]     = accA + sbh1[2*wv];
          gh1l[2*wv + 1] = accB + sbh1[2*wv + 1];
        }
      } else if (wv == 6) {
        float acc = wred64(qdot4(wreg[0], wreg[1], wreg[2], wreg[3], y0, y1, y2, y3));
        if (lane == 0)
          stq(tEU + ((size_t)c * NWG + wg) * 8 + 1, vhW * fast_tanh(acc + bhW), tg);
      } else {
        float acc = wred64(qdot4(wreg[0], wreg[1], wreg[2], wreg[3], y0, y1, y2, y3));
        if (lane == 0)
          stq(tEU + ((size_t)c * NWG + wg) * 8 + 3, acc, tg);
      }
    }
  }
}

// ---------------- output head ----------------
__global__ __launch_bounds__(256) void k_head(
    const float* __restrict__ FC1, const float* __restrict__ Wf2,
    const float* __restrict__ bf2, float* __restrict__ out, float* __restrict__ rowp)
{
  __shared__ float fcb[256 * 32];
  const int v = blockIdx.x * 256 + threadIdx.x;
  const bool ok = v < VOC;
  float wf[32];
  float bb = 0.f;
  if (ok) {
    const float4* W4 = (const float4*)(Wf2 + (size_t)v * 32);
    #pragma unroll
    for (int q = 0; q < 8; ++q) ((float4*)wf)[q] = W4[q];
    bb = bf2[v];
  }
  const int wv = threadIdx.x >> 6;
  #pragma unroll 1
  for (int half = 0; half < 2; ++half) {
    __syncthreads();
    for (int i = threadIdx.x; i < 256 * 32 / 4; i += 256)
      ((float4*)fcb)[i] = ((const float4*)(FC1 + half * 256 * 32))[i];
    __syncthreads();
    #pragma unroll 1
    for (int tt = 0; tt < 256; ++tt) {
      const int t = half * 256 + tt;
      const float4* f4 = (const float4*)(fcb + tt * 32);
      float acc = bb;
      #pragma unroll
      for (int q = 0; q < 8; ++q) {
        float4 f = f4[q];
        acc = fmaf(wf[4*q+0], f.x, acc);
        acc = fmaf(wf[4*q+1], f.y, acc);
        acc = fmaf(wf[4*q+2], f.z, acc);
        acc = fmaf(wf[4*q+3], f.w, acc);
      }
      const float w = ok ? __expf(acc) : 0.f;
      if (ok) out[(size_t)t * VOC + v] = w;
      float r = wred64(w);
      if ((threadIdx.x & 63) == 0)
        rowp[(size_t)t * NPART + (size_t)blockIdx.x * 4 + wv] = r;
    }
  }
}

__global__ __launch_bounds__(256) void k_rowsum(const float* __restrict__ rowp, float* __restrict__ inv) {
  const int t = blockIdx.x;
  float acc = 0.f;
  for (int i = threadIdx.x; i < NPART; i += 256) acc += rowp[(size_t)t * NPART + i];
  acc = wred64(acc);
  __shared__ float sr[4];
  if ((threadIdx.x & 63) == 0) sr[threadIdx.x >> 6] = acc;
  __syncthreads();
  if (threadIdx.x == 0) inv[t] = 1.f / (sr[0] + sr[1] + sr[2] + sr[3]);
}

__global__ __launch_bounds__(256) void k_scale(float* __restrict__ out, const float* __restrict__ inv) {
  const int t = blockIdx.y;
  const float s = inv[t];
  const size_t base = (size_t)t * VOC;
  const int v0 = blockIdx.x * 2048 + threadIdx.x;
  #pragma unroll
  for (int k = 0; k < 8; ++k) {
    const int v = v0 + k * 256;
    if (v < VOC) out[base + v] *= s;
  }
}

extern "C" void kernel_launch(void* const* d_in, const int* in_sizes, int n_in,
                              void* d_out, int out_size, void* d_ws, size_t ws_size,
                              hipStream_t stream) {
  const int*   dec  = (const int*)  d_in[0];
  const float* enc  = (const float*)d_in[1];
  const float* emb  = (const float*)d_in[2];
  const float* Wax  = (const float*)d_in[3];
  const float* Wac  = (const float*)d_in[4];
  const float* ba   = (const float*)d_in[5];
  const float* va   = (const float*)d_in[6];
  const float* vab  = (const float*)d_in[7];
  const float* Wih0 = (const float*)d_in[8];
  const float* bih0 = (const float*)d_in[9];
  const float* Whh0 = (const float*)d_in[10];
  const float* bhh0 = (const float*)d_in[11];
  const float* Wih1 = (const float*)d_in[12];
  const float* bih1 = (const float*)d_in[13];
  const float* Whh1 = (const float*)d_in[14];
  const float* bhh1 = (const float*)d_in[15];
  const float* Wh   = (const float*)d_in[16];
  const float* bh   = (const float*)d_in[17];
  const float* vh   = (const float*)d_in[18];
  const float* vhb  = (const float*)d_in[19];
  const float* Wf1  = (const float*)d_in[20];
  const float* bf1  = (const float*)d_in[21];
  const float* Wf2  = (const float*)d_in[22];
  const float* bf2  = (const float*)d_in[23];
  float* out = (float*)d_out;
  float* ws  = (float*)d_ws;

  k_init<<<64, 256, 0, stream>>>(ws);   // 64*256 == TG_TOT

  // Genc[r][s] = Wih0[r, :1024] . enc[s]          (M=3072, N=512)
  k_gemm<<<dim3(8, 48), 256, 0, stream>>>(Wih0, 2048, nullptr, enc, 1024, 0,
                                          nullptr, ws + WS_GENC, 512, G3, S_LEN, 0);
  // gi_tok[t][r] = emb[dec[t]] . Wih0[r, 1024:] + bih0[r]   (M=512, N=3072)
  k_gemm<<<dim3(48, 8), 256, 0, stream>>>(emb, 1024, dec, Wih0, 2048, 1024,
                                          bih0, ws + WS_GITOK, G3, T_LEN, G3, 0);
  // Ex[s][i] = enc[s] . Wa_x[i] + ba[i]           (M=512, N=256)
  k_gemm<<<dim3(4, 8), 256, 0, stream>>>(enc, 1024, nullptr, Wax, 1024, 0,
                                         ba, ws + WS_EX, AD, S_LEN, AD, 0);

  k_recur<<<NWG, NT, 0, stream>>>(ws, Whh0, bhh0, Wih1, bih1, Whh1, bhh1,
                                  Wh, bh, vh, vhb, va, vab, Wac);

  // FC1[t] = relu(Wf1 @ H1[t] + bf1)              (M=512, N=32)
  k_gemm<<<dim3(1, 8), 256, 0, stream>>>(ws + WS_H1, 1024, nullptr, Wf1, 1024, 0,
                                         bf1, ws + WS_FC1, 32, T_LEN, 32, 1);

  k_head<<<197, 256, 0, stream>>>(ws + WS_FC1, Wf2, bf2, out, ws + WS_ROWP);
  k_rowsum<<<512, 256, 0, stream>>>(ws + WS_ROWP, ws + WS_INV);
  k_scale<<<dim3(25, 512), 256, 0, stream>>>(out, ws + WS_INV);
}